// Round 10
// baseline (137.711 us; speedup 1.0000x reference)
//
#include <hip/hip_runtime.h>

// EmotionCaps dynamic routing (fp32 I/O):
// u: [B=64, N=1024, I=64] f32; W: [N=1024, E=8, O=32, I=64] f32
// out: v [B=64, E=8, O=32] f32
//
// 5 dispatches (kernel boundaries = only cross-block sync; measured dead
// ends: grid.sync 110us/sync r3, 64-block fusion 87us r6, fence+counter
// 190us/pass r7):
//   k_uhat   : u_hat bf16 (32MB ws) via 16x16x32 bf16 MFMA; zeroes s0/s1/s2.
//              u_hat stored in REGISTER-NATIVE tiled layout (no LDS
//              transpose epilogue): uint addr = n*8192 + w*2048 + nt*512
//              + mt*128 + j*64 + lane;  uint = bf16 pair
//              (b = mt*16+g*4+2j, b+1); lane = g*16 + m16.
//              [r9 FAILED with strides 2048/512 — blocks overlapped; fixed.]
//   k_route 0: c=1/8            -> atomicAdd s0
//   k_route 1: v0=squash(s0)    -> logits=uh.v0  -> atomicAdd s1
//   k_route 2: v01=v0+v1        -> logits=uh.v01 -> atomicAdd s2
//   k_out    : out = squash(s2)
// Logit identity b2 = uh.(v0+v1) verified rounds 4-8 (absmax stable 0.0039).

#define B_  64
#define N_  1024
#define I_  64
#define E_  8
#define O_  32
#define EO_ 256
#define PAD_ 72

typedef __bf16 bf16x8 __attribute__((ext_vector_type(8)));
typedef __bf16 bf16x4v __attribute__((ext_vector_type(4)));
typedef float  f32x4  __attribute__((ext_vector_type(4)));

__device__ __forceinline__ float bf2f(unsigned int h) {
    unsigned int x = (h & 0xffffu) << 16;
    return __builtin_bit_cast(float, x);
}
__device__ __forceinline__ void cvt_store4(unsigned short* dst, float4 q) {
    bf16x4v v;
    v[0] = (__bf16)q.x; v[1] = (__bf16)q.y; v[2] = (__bf16)q.z; v[3] = (__bf16)q.w;
    *(bf16x4v*)dst = v;
}
__device__ __forceinline__ bf16x8 cvt8(const float* __restrict__ p) {
    float4 q0 = *(const float4*)p;
    float4 q1 = *(const float4*)(p + 4);
    bf16x8 a;
    a[0] = (__bf16)q0.x; a[1] = (__bf16)q0.y; a[2] = (__bf16)q0.z; a[3] = (__bf16)q0.w;
    a[4] = (__bf16)q1.x; a[5] = (__bf16)q1.y; a[6] = (__bf16)q1.z; a[7] = (__bf16)q1.w;
    return a;
}
__device__ __forceinline__ unsigned pack2(float a, float b) {
    __bf16 ha = (__bf16)a, hb = (__bf16)b;
    return (unsigned)__builtin_bit_cast(unsigned short, ha)
         | ((unsigned)__builtin_bit_cast(unsigned short, hb) << 16);
}
// squash over the 32-elem o-group; lane holds 4 o-consecutive values of its
// 8-lane e-group; shfl 1,2,4 stays inside the e-group. (verified r8)
__device__ __forceinline__ float4 squash4(float4 s4) {
    float sq = s4.x * s4.x + s4.y * s4.y + s4.z * s4.z + s4.w * s4.w;
    sq += __shfl_xor(sq, 1);
    sq += __shfl_xor(sq, 2);
    sq += __shfl_xor(sq, 4);
    float nrm = sqrtf(sq);
    float sc = sq / ((1.f + sq) * (nrm + 1e-8f));
    return make_float4(sc * s4.x, sc * s4.y, sc * s4.z, sc * s4.w);
}

// ---------------------------------------------------------------------------
// K1: one block per n. D[64b x 256eo] = u[:,n,:] . W[n]^T via 16x16x32 bf16
// MFMA (fragment layouts verified r3-8). u staged in LDS (A-frags, 9216 B
// only -> high occupancy); W frags streamed from global; D stored DIRECTLY
// in register-native layout (lane-contiguous 256B per instr, no LDS epilogue,
// single barrier). Blocks 0..47 zero s0|s1|s2 (1 KB each).
// ---------------------------------------------------------------------------
__global__ __launch_bounds__(256) void k_uhat(const float* __restrict__ u,
                                              const float* __restrict__ W,
                                              unsigned int* __restrict__ uh32,
                                              float* __restrict__ s012) {
    const int n = blockIdx.x;
    const int t = threadIdx.x;
    const int w = t >> 6, l = t & 63;
    const int m16 = l & 15, g = l >> 4;

    if (n < 48) {   // 48 blocks x 256 threads x float4 = 49152 floats = s0|s1|s2
        ((float4*)s012)[n * 256 + t] = make_float4(0.f, 0.f, 0.f, 0.f);
    }

    __shared__ __align__(16) unsigned short ul[B_ * PAD_];   // 9216 B

#pragma unroll
    for (int j = 0; j < 4; ++j) {
        int idx = j * 256 + t;
        int b = idx >> 4, c = idx & 15;
        float4 q = *(const float4*)(u + (size_t)b * (N_ * I_) + n * I_ + c * 4);
        cvt_store4(&ul[b * PAD_ + c * 4], q);
    }
    __syncthreads();

    bf16x8 afr[4][2];   // A[m=lane&15][k=(lane>>4)*8+j]
#pragma unroll
    for (int mt = 0; mt < 4; ++mt)
#pragma unroll
        for (int ks = 0; ks < 2; ++ks)
            afr[mt][ks] = *(const bf16x8*)&ul[(mt * 16 + m16) * PAD_ + ks * 32 + g * 8];

    f32x4 acc[4][4];
#pragma unroll
    for (int nt = 0; nt < 4; ++nt)
#pragma unroll
        for (int mt = 0; mt < 4; ++mt)
            acc[nt][mt] = (f32x4){0.f, 0.f, 0.f, 0.f};

    const float* Wn = W + (size_t)n * (EO_ * I_);
#pragma unroll
    for (int nt = 0; nt < 4; ++nt) {
        const int eo = w * 64 + nt * 16 + m16;
        const float* wp = Wn + (size_t)eo * I_ + g * 8;
        bf16x8 b0 = cvt8(wp);
        bf16x8 b1 = cvt8(wp + 32);
#pragma unroll
        for (int mt = 0; mt < 4; ++mt) {
            acc[nt][mt] = __builtin_amdgcn_mfma_f32_16x16x32_bf16(afr[mt][0], b0, acc[nt][mt], 0, 0, 0);
            acc[nt][mt] = __builtin_amdgcn_mfma_f32_16x16x32_bf16(afr[mt][1], b1, acc[nt][mt], 0, 0, 0);
        }
    }

    // Direct store, register-native layout. D lane map (verified r3-8):
    // reg r of acc[nt][mt] = (b = mt*16+g*4+r, eo = w*64+nt*16+m16).
    // Pack r-pairs -> uint; addr = n*8192 + w*2048 + nt*512 + mt*128 + j*64 + l.
    unsigned int* dst = uh32 + (size_t)n * 8192 + (size_t)w * 2048 + l;
#pragma unroll
    for (int nt = 0; nt < 4; ++nt)
#pragma unroll
        for (int mt = 0; mt < 4; ++mt)
#pragma unroll
            for (int j = 0; j < 2; ++j)
                dst[(size_t)(nt * 8 + mt * 2 + j) * 64] =
                    pack2(acc[nt][mt][2 * j], acc[nt][mt][2 * j + 1]);
}

// ---------------------------------------------------------------------------
// K2: one routing pass, dual-b. 1024 blocks = (b-pair p, chunk of 32 n);
// p -> (mt = p>>3, j = (p>>2)&1, g = p&3), b0 = mt*16+g*4+2j, b1 = b0+1.
// Wave handles 8 n; lane l owns eo = 4l..4l+3 (identical lane<->eo map as
// r2-8: (w_e,nt_e,q) = (l>>4, (l>>2)&3, l&3)); one aligned uint4 per
// (n, lane) yields 4 eo x 2 b:
//   uint addr(n,k) = n*8192 + w_e*2048 + nt_e*512 + mt*128 + j*64 + g*16+4q+k.
// Shuffle math verified r2-8: dot over o = shfl 1,2,4; softmax over E =
// shfl 8,16,32. 2 atomicAdds per thread into s[b][eo].
// ---------------------------------------------------------------------------
__global__ __launch_bounds__(256) void k_route(const unsigned int* __restrict__ uh32,
                                               const float* __restrict__ s0,
                                               const float* __restrict__ s1,
                                               float* __restrict__ tgt,
                                               int it) {
    const int blk = blockIdx.x;
    const int p = blk >> 5, chunk = blk & 31;
    const int mt = p >> 3, j = (p >> 2) & 1, g = p & 3;
    const int b0 = mt * 16 + g * 4 + 2 * j;     // b1 = b0 + 1
    const int t = threadIdx.x, wave = t >> 6, l = t & 63;
    const int w_e = l >> 4, nt_e = (l >> 2) & 3, q = l & 3;

    const unsigned int* base = uh32
        + (size_t)w_e * 2048 + (size_t)nt_e * 512
        + (size_t)(mt * 2 + j) * 64 + g * 16 + 4 * q;
    const int n0 = chunk * 32 + wave * 8;

    float4 v40 = make_float4(0.f, 0.f, 0.f, 0.f), v41 = v40;
    if (it) {
        v40 = squash4(*(const float4*)(s0 + b0 * EO_ + 4 * l));
        v41 = squash4(*(const float4*)(s0 + (b0 + 1) * EO_ + 4 * l));
        if (it == 2) {
            float4 w0 = squash4(*(const float4*)(s1 + b0 * EO_ + 4 * l));
            float4 w1 = squash4(*(const float4*)(s1 + (b0 + 1) * EO_ + 4 * l));
            v40.x += w0.x; v40.y += w0.y; v40.z += w0.z; v40.w += w0.w;
            v41.x += w1.x; v41.y += w1.y; v41.z += w1.z; v41.w += w1.w;
        }
    }

    float a0[4] = {0.f, 0.f, 0.f, 0.f};
    float a1[4] = {0.f, 0.f, 0.f, 0.f};
#pragma unroll 1
    for (int nn = 0; nn < 8; ++nn) {
        uint4 pk = *(const uint4*)(base + (size_t)(n0 + nn) * 8192);
        unsigned int pu[4] = {pk.x, pk.y, pk.z, pk.w};
        float x0[4], x1[4];
#pragma unroll
        for (int k = 0; k < 4; ++k) {
            x0[k] = bf2f(pu[k]);          // b0: low half
            x1[k] = bf2f(pu[k] >> 16);    // b1: high half
        }
        float c0, c1;
        if (it == 0) {
            c0 = 0.125f; c1 = 0.125f;
        } else {
            float pd0 = x0[0] * v40.x + x0[1] * v40.y + x0[2] * v40.z + x0[3] * v40.w;
            float pd1 = x1[0] * v41.x + x1[1] * v41.y + x1[2] * v41.z + x1[3] * v41.w;
            pd0 += __shfl_xor(pd0, 1);  pd1 += __shfl_xor(pd1, 1);
            pd0 += __shfl_xor(pd0, 2);  pd1 += __shfl_xor(pd1, 2);
            pd0 += __shfl_xor(pd0, 4);  pd1 += __shfl_xor(pd1, 4);
            float m0 = pd0, m1 = pd1;
            m0 = fmaxf(m0, __shfl_xor(m0, 8));   m1 = fmaxf(m1, __shfl_xor(m1, 8));
            m0 = fmaxf(m0, __shfl_xor(m0, 16));  m1 = fmaxf(m1, __shfl_xor(m1, 16));
            m0 = fmaxf(m0, __shfl_xor(m0, 32));  m1 = fmaxf(m1, __shfl_xor(m1, 32));
            float e0 = __expf(pd0 - m0), e1 = __expf(pd1 - m1);
            float sm0 = e0, sm1 = e1;
            sm0 += __shfl_xor(sm0, 8);   sm1 += __shfl_xor(sm1, 8);
            sm0 += __shfl_xor(sm0, 16);  sm1 += __shfl_xor(sm1, 16);
            sm0 += __shfl_xor(sm0, 32);  sm1 += __shfl_xor(sm1, 32);
            c0 = e0 * __builtin_amdgcn_rcpf(sm0);
            c1 = e1 * __builtin_amdgcn_rcpf(sm1);
        }
#pragma unroll
        for (int k = 0; k < 4; ++k) {
            a0[k] = fmaf(c0, x0[k], a0[k]);
            a1[k] = fmaf(c1, x1[k], a1[k]);
        }
    }

    __shared__ __align__(16) float red[4][2 * EO_];   // 8 KB
    *(float4*)&red[wave][4 * l]        = make_float4(a0[0], a0[1], a0[2], a0[3]);
    *(float4*)&red[wave][EO_ + 4 * l]  = make_float4(a1[0], a1[1], a1[2], a1[3]);
    __syncthreads();
    float t0 = red[0][t] + red[1][t] + red[2][t] + red[3][t];
    float t1 = red[0][EO_ + t] + red[1][EO_ + t] + red[2][EO_ + t] + red[3][EO_ + t];
    atomicAdd(&tgt[b0 * EO_ + t], t0);
    atomicAdd(&tgt[(b0 + 1) * EO_ + t], t1);
}

// ---------------------------------------------------------------------------
// K3: out = squash(s2). 64 blocks x 256 (t = eo; o-group = 32 lanes).
// ---------------------------------------------------------------------------
__global__ __launch_bounds__(256) void k_out(const float* __restrict__ s2,
                                             float* __restrict__ out) {
    const int b = blockIdx.x, t = threadIdx.x;
    float sv = s2[b * EO_ + t];
    float sq = sv * sv;
    sq += __shfl_xor(sq, 1);
    sq += __shfl_xor(sq, 2);
    sq += __shfl_xor(sq, 4);
    sq += __shfl_xor(sq, 8);
    sq += __shfl_xor(sq, 16);
    float nrm = sqrtf(sq);
    out[b * EO_ + t] = sq / ((1.f + sq) * (nrm + 1e-8f)) * sv;
}

extern "C" void kernel_launch(void* const* d_in, const int* in_sizes, int n_in,
                              void* d_out, int out_size, void* d_ws, size_t ws_size,
                              hipStream_t stream) {
    const float* u = (const float*)d_in[0];     // f32 [64,1024,64]
    const float* W = (const float*)d_in[1];     // f32 [1024,8,32,64]
    float* out = (float*)d_out;                 // f32 [64,8,32]

    char* ws = (char*)d_ws;
    unsigned int* uh32 = (unsigned int*)ws;      // 33,554,432 B  u_hat bf16 (tiled)
    float* s0 = (float*)(ws + 33554432);         // 65,536 B
    float* s1 = s0 + B_ * EO_;                   // 65,536 B
    float* s2 = s1 + B_ * EO_;                   // 65,536 B

    k_uhat <<<dim3(N_),   dim3(256), 0, stream>>>(u, W, uh32, s0);
    k_route<<<dim3(1024), dim3(256), 0, stream>>>(uh32, s0, s1, s0, 0);
    k_route<<<dim3(1024), dim3(256), 0, stream>>>(uh32, s0, s1, s1, 1);
    k_route<<<dim3(1024), dim3(256), 0, stream>>>(uh32, s0, s1, s2, 2);
    k_out  <<<dim3(B_),   dim3(256), 0, stream>>>(s2, out);
}